// Round 12
// baseline (31.519 us; speedup 1.0000x reference)
//
#include <hip/hip_runtime.h>

#define TWO_PI 6.2831853071795864769f

// ws layout (bytes):
//   x1   f32[12*6*256] @ 0       (73728)   stage-0 output (LLC path)
//   x2   f32[12*6*256] @ 73728   (73728)   stage-1 output
//   bar  int[16]       @ 147456  (64)      per-b barrier counters (memset'd)
//
// ONE dispatch, 48 blocks x 512 threads = 6 b x 8 e-tiles(32).
// Per-CU ingest wall (all rounds r3-r11: ~10 B/cyc/CU, MSHR/latency-bound,
// independent of L2-vs-HBM sourcing) is attacked by tiling e: each block
// register-caches m[256 d][32 e] = 64 KB (vs r11's 512 KB) and computes all
// 12 h for its tile -> no h-redundancy. Stage chaining: only the 8 blocks of
// the SAME b must sync -> per-b barrier (count to 8) with r10's proven
// relaxed agent-scope protocol (no wbl2/inv storms; __syncthreads drains
// vmcnt so x-stores are LLC-visible before the counter increment).
// Scatter = sparse corrections (val_s - P1[pos]) at last-write-wins winners,
// resolved per-block via r11's LDS hash (key=(d,e), payload=k, atomicMax).

__global__ __launch_bounds__(512, 2) void fused_all(
    const float* __restrict__ P1, const float* __restrict__ P2,
    const float* __restrict__ P3, const float* __restrict__ T4,
    const int* __restrict__ p5, const int* __restrict__ p6,
    const int* __restrict__ p7, const int* __restrict__ p8,
    const float* __restrict__ f1, const float* __restrict__ ph1,
    const float* __restrict__ T11, const float* __restrict__ f2,
    const float* __restrict__ ph2, const float* __restrict__ T14,
    const float* __restrict__ f3, const float* __restrict__ ph3,
    float* __restrict__ x1, float* __restrict__ x2,
    int* __restrict__ bar, float* __restrict__ out, int K)
{
    __shared__ float v[12 * 256];          // 12 KB  current stage input
    __shared__ float ps[16][12][32];       // 24 KB  per-dgroup partials
    __shared__ float om[12][32];           // 1.5 KB merged output tile
    __shared__ float mf[3][32];            //        modulation (pre-inverted)
    __shared__ unsigned hmap[4096];        // 16 KB  winner hash (this b)
    __shared__ unsigned short wde[2048];   // 4 KB   winner (d<<8)|e
    __shared__ float wv0[2048], wv1[2048], wv2[2048];  // 24 KB corrections
    __shared__ int nwl;

    const int tid = (int)threadIdx.x;
    const int blk = (int)blockIdx.x;
    const int b = blk % 6;
    const int t = blk / 6;                 // 0..7
    const int e0 = t << 5;
    const int dg = tid >> 5;               // 0..15 (16 d-rows each)
    const int el = tid & 31;               // e = e0 + el

    // ---- init (LDS + small loads) ----
    for (int i = tid; i < 4096; i += 512) hmap[i] = 0xFFFFFFFFu;
    for (int i = tid; i < 3072; i += 512)
        v[i] = P2[(((i >> 8) * 6 + b) << 8) | (i & 255)];
    if (tid < 96) {
        int s = tid >> 5, j = tid & 31;
        float fr = (s == 0) ? f1[0]  : (s == 1) ? f2[0]  : f3[0];
        float ph = (s == 0) ? ph1[0] : (s == 1) ? ph2[0] : ph3[0];
        float sn = __sinf((float)(e0 + j) * TWO_PI * fr + ph);
        float mm = sn * sn * 0.1f + 0.95f;
        mf[s][j] = (s == 1) ? mm : 1.0f / mm;   // s0: /m, s1: *m, s2: /m
    }
    if (tid == 0) nwl = 0;
    __syncthreads();

    // ---- issue m-tile loads (64 KB/CU), overlap with hash insert ----
    const float* P1r = P1 + (b << 16) + (dg << 12) + e0 + el;
    const float* P3r = P3 + (b << 16) + (dg << 12) + e0 + el;
    float m_t[16];
    #pragma unroll
    for (int dd = 0; dd < 16; ++dd)
        m_t[dd] = fmaf(P3r[dd << 8], 0.975f, P1r[dd << 8]);

    // ---- hash insert: last-write-wins = max k per (d,e), this b only ----
    for (int k = tid; k < K; k += 512) {
        if (p5[k] != b) continue;
        unsigned key = ((unsigned)p7[k] << 8) | (unsigned)p8[k];
        unsigned mine = (key << 12) | (unsigned)k;       // k < 4096
        unsigned hh = (key * 2654435761u) >> 20;         // [0,4096)
        for (;;) {
            unsigned prev = atomicCAS(&hmap[hh], 0xFFFFFFFFu, mine);
            if (prev == 0xFFFFFFFFu) break;
            if ((prev >> 12) == key) { atomicMax(&hmap[hh], mine); break; }
            hh = (hh + 1) & 4095u;
        }
    }
    __syncthreads();

    // ---- winner readback -> compact LDS correction lists ----
    for (int k = tid; k < K; k += 512) {
        if (p5[k] != b) continue;
        unsigned key = ((unsigned)p7[k] << 8) | (unsigned)p8[k];
        unsigned hh = (key * 2654435761u) >> 20;
        unsigned cur;
        for (;;) {
            cur = hmap[hh];
            if ((cur >> 12) == key) break;
            hh = (hh + 1) & 4095u;
        }
        if ((cur & 0xFFFu) == (unsigned)k) {             // last write wins
            int c = p6[k];
            float p1v = P1[(b << 16) | key];
            int w = atomicAdd(&nwl, 1);
            wde[w] = (unsigned short)key;
            wv0[w] = T4 [b * 256 + c] - p1v;
            wv1[w] = T11[b * 256 + c] - p1v;
            wv2[w] = T14[b * 256 + c] - p1v;
        }
    }
    __syncthreads();
    const int nw = nwl;

    // ---- three chained stages ----
    for (int s = 0; s < 3; ++s) {
        // dense: acc[h] = sum_d v[h][d] * m[d][e]  (m in regs, v LDS bcast)
        float acc[12];
        #pragma unroll
        for (int h = 0; h < 12; ++h) acc[h] = 0.f;
        #pragma unroll
        for (int h = 0; h < 12; ++h) {
            const float* vh = &v[(h << 8) + (dg << 4)];
            float4 q0 = *(const float4*)&vh[0];
            float4 q1 = *(const float4*)&vh[4];
            float4 q2 = *(const float4*)&vh[8];
            float4 q3 = *(const float4*)&vh[12];
            acc[h] = fmaf(q0.x, m_t[0], acc[h]);
            acc[h] = fmaf(q0.y, m_t[1], acc[h]);
            acc[h] = fmaf(q0.z, m_t[2], acc[h]);
            acc[h] = fmaf(q0.w, m_t[3], acc[h]);
            acc[h] = fmaf(q1.x, m_t[4], acc[h]);
            acc[h] = fmaf(q1.y, m_t[5], acc[h]);
            acc[h] = fmaf(q1.z, m_t[6], acc[h]);
            acc[h] = fmaf(q1.w, m_t[7], acc[h]);
            acc[h] = fmaf(q2.x, m_t[8], acc[h]);
            acc[h] = fmaf(q2.y, m_t[9], acc[h]);
            acc[h] = fmaf(q2.z, m_t[10], acc[h]);
            acc[h] = fmaf(q2.w, m_t[11], acc[h]);
            acc[h] = fmaf(q3.x, m_t[12], acc[h]);
            acc[h] = fmaf(q3.y, m_t[13], acc[h]);
            acc[h] = fmaf(q3.z, m_t[14], acc[h]);
            acc[h] = fmaf(q3.w, m_t[15], acc[h]);
        }
        #pragma unroll
        for (int h = 0; h < 12; ++h) ps[dg][h][el] = acc[h];
        __syncthreads();

        // merge 16 -> 1
        if (tid < 384) {
            int h = tid >> 5, e = tid & 31;
            float sum = 0.f;
            #pragma unroll
            for (int g = 0; g < 16; ++g) sum += ps[g][h][e];
            om[h][e] = sum;
        }
        __syncthreads();

        // sparse corrections (in-tile winners)
        const float* wvs = (s == 0) ? wv0 : (s == 1) ? wv1 : wv2;
        for (int i = tid; i < nw; i += 512) {
            unsigned de = wde[i];
            int e_w = (int)(de & 255u) - e0;
            if ((unsigned)e_w >= 32u) continue;
            int d_w = (int)(de >> 8);
            float val = wvs[i];
            #pragma unroll
            for (int h = 0; h < 12; ++h)
                atomicAdd(&om[h][e_w], v[(h << 8) | d_w] * val);
        }
        __syncthreads();

        // modulate + store (+ per-b barrier and v reload if not last)
        if (s == 2) {
            if (tid < 384) {
                int h = tid >> 5, e = tid & 31;
                out[((h * 6 + b) << 8) | (e0 + e)] = om[h][e] * mf[2][e];
            }
        } else {
            float* dst = (s == 0) ? x1 : x2;
            if (tid < 384) {
                int h = tid >> 5, e = tid & 31;
                __hip_atomic_store(&dst[((h * 6 + b) << 8) | (e0 + e)],
                                   om[h][e] * mf[s][e],
                                   __ATOMIC_RELAXED, __HIP_MEMORY_SCOPE_AGENT);
            }
            // drain vmcnt for ALL waves' stores before the counter increment
            __syncthreads();
            if (tid == 0) {
                __hip_atomic_fetch_add(&bar[s * 6 + b], 1, __ATOMIC_RELAXED,
                                       __HIP_MEMORY_SCOPE_AGENT);
                while (__hip_atomic_load(&bar[s * 6 + b], __ATOMIC_RELAXED,
                                         __HIP_MEMORY_SCOPE_AGENT) < 8)
                    __builtin_amdgcn_s_sleep(1);
            }
            __syncthreads();
            for (int i = tid; i < 3072; i += 512)
                v[i] = __hip_atomic_load(
                    &dst[(((i >> 8) * 6 + b) << 8) | (i & 255)],
                    __ATOMIC_RELAXED, __HIP_MEMORY_SCOPE_AGENT);
            __syncthreads();
        }
    }
}

extern "C" void kernel_launch(void* const* d_in, const int* in_sizes, int n_in,
                              void* d_out, int out_size, void* d_ws, size_t ws_size,
                              hipStream_t stream)
{
    (void)n_in; (void)out_size; (void)ws_size;
    const float* P1  = (const float*)d_in[0];
    const float* P2  = (const float*)d_in[1];
    const float* P3  = (const float*)d_in[2];
    const float* T4  = (const float*)d_in[3];
    const int*   p5  = (const int*)d_in[4];
    const int*   p6  = (const int*)d_in[5];
    const int*   p7  = (const int*)d_in[6];
    const int*   p8  = (const int*)d_in[7];
    const float* f1  = (const float*)d_in[8];
    const float* ph1 = (const float*)d_in[9];
    const float* T11 = (const float*)d_in[10];
    const float* f2  = (const float*)d_in[11];
    const float* ph2 = (const float*)d_in[12];
    const float* T14 = (const float*)d_in[13];
    const float* f3  = (const float*)d_in[14];
    const float* ph3 = (const float*)d_in[15];
    float* out = (float*)d_out;
    int K = in_sizes[4];

    char* ws = (char*)d_ws;
    float* x1  = (float*)(ws);
    float* x2  = (float*)(ws + 73728);
    int*   bar = (int*)  (ws + 147456);

    // zero the barrier counters every call (captured as a memset node)
    hipMemsetAsync(bar, 0, 64, stream);
    hipLaunchKernelGGL(fused_all, dim3(48), dim3(512), 0, stream,
                       P1, P2, P3, T4, p5, p6, p7, p8,
                       f1, ph1, T11, f2, ph2, T14, f3, ph3,
                       x1, x2, bar, out, K);
}

// Round 13
// 21.632 us; speedup vs baseline: 1.4571x; 1.4571x over previous
//
#include <hip/hip_runtime.h>

#define TWO_PI 6.2831853071795864769f

// ONE dispatch, NO barriers, NO ws. Grid = 96 blocks, blk = h*8 + b:
// blk % 8 = b => the 12 h-chains of batch b all land on XCD b, sharing that
// XCD's 4MB L2 for P1_b/P3_b (512 KB).
//
// r13 change vs r11 (single variable): STAGGERED load order. r11's 12
// co-XCD blocks started the m-fill simultaneously on the SAME lines -> all
// missed together to HBM (L2 never served anyone; swizzle bought only 11%).
// Here block h starts its 16-row fill at row (j+h)&15, so at any instant the
// 12 blocks request DIFFERENT lines; each line is HBM-fetched once and the
// other 11 blocks hit warm L2 (~200cyc vs ~900cyc -> ~4.6x ingest rate).
// m4[j] stores the PERMUTED row (static reg index, rule #20); the matvec
// compensates via wave-uniform LDS read v[(dg<<4) + ((j+roff)&15)].
//
// Scatter = sparse corrections (val_s - P1[pos]) at last-write-wins winners,
// resolved per-block by an LDS hash (key=(d,e), payload=k, atomicMax).
__global__ __launch_bounds__(1024, 4) void fused_chain(
    const float* __restrict__ P1, const float* __restrict__ P2,
    const float* __restrict__ P3, const float* __restrict__ T4,
    const int* __restrict__ p5, const int* __restrict__ p6,
    const int* __restrict__ p7, const int* __restrict__ p8,
    const float* __restrict__ f1, const float* __restrict__ ph1,
    const float* __restrict__ T11, const float* __restrict__ f2,
    const float* __restrict__ ph2, const float* __restrict__ T14,
    const float* __restrict__ f3, const float* __restrict__ ph3,
    float* __restrict__ out, int K)
{
    const int blk = (int)blockIdx.x;
    const int b = blk & 7;               // = blk % 8 = XCD id
    if (b >= 6) return;
    const int h = blk >> 3;              // 0..11

    __shared__ float v[256];
    __shared__ float pv[16][256];          // 16 KB partials
    __shared__ float modl[3][256];
    __shared__ unsigned hmap[4096];        // (key<<12)|k ; empty=0xFFFFFFFF
    __shared__ unsigned short wde[2048];   // winner (d<<8)|e
    __shared__ float wv0[2048], wv1[2048], wv2[2048];
    __shared__ int nw;

    const int tid = (int)threadIdx.x;
    const int dg = tid >> 6;               // 0..15
    const int eg = tid & 63;               // 0..63
    const int roff = h & 15;               // per-block row stagger

    // ---- phase 1: issue dense m loads FIRST, staggered start row ----
    const float4* P1v = (const float4*)P1;
    const float4* P3v = (const float4*)P3;
    const int rbase = (b << 8) + (dg << 4);
    float4 m4[16];                         // m4[j] = row (j+roff)&15
    #pragma unroll
    for (int j = 0; j < 16; ++j) {
        int i = (j + roff) & 15;           // runtime addr math only
        float4 a = P1v[(rbase + i) * 64 + eg];
        float4 c = P3v[(rbase + i) * 64 + eg];
        m4[j].x = fmaf(c.x, 0.975f, a.x);
        m4[j].y = fmaf(c.y, 0.975f, a.y);
        m4[j].z = fmaf(c.z, 0.975f, a.z);
        m4[j].w = fmaf(c.w, 0.975f, a.w);
    }

    // ---- small init (overlaps with loads) ----
    if (tid < 256) v[tid] = P2[(h * 6 + b) * 256 + tid];
    if (tid < 768) {
        int s = tid >> 8, ee = tid & 255;
        float fr = (s == 0) ? f1[0]  : (s == 1) ? f2[0]  : f3[0];
        float ph = (s == 0) ? ph1[0] : (s == 1) ? ph2[0] : ph3[0];
        float sn = __sinf((float)ee * TWO_PI * fr + ph);
        float mm = sn * sn * 0.1f + 0.95f;
        modl[s][ee] = (s == 1) ? mm : 1.0f / mm;   // s0: /m, s1: *m, s2: /m
    }
    for (int i = tid; i < 4096; i += 1024) hmap[i] = 0xFFFFFFFFu;
    if (tid == 0) nw = 0;
    __syncthreads();

    // ---- phase 2: direct hash insert, last-write-wins = max k per (d,e) ----
    for (int k = tid; k < K; k += 1024) {
        if (p5[k] != b) continue;
        unsigned key = ((unsigned)p7[k] << 8) | (unsigned)p8[k];   // 16 bits
        unsigned mine = (key << 12) | (unsigned)k;                 // k < 4096
        unsigned hh = (key * 2654435761u) >> 20;                   // [0,4096)
        for (;;) {
            unsigned prev = atomicCAS(&hmap[hh], 0xFFFFFFFFu, mine);
            if (prev == 0xFFFFFFFFu) break;
            if ((prev >> 12) == key) { atomicMax(&hmap[hh], mine); break; }
            hh = (hh + 1) & 4095u;
        }
    }
    __syncthreads();

    // ---- phase 3: winner readback -> sparse corrections ----
    for (int k = tid; k < K; k += 1024) {
        if (p5[k] != b) continue;
        unsigned key = ((unsigned)p7[k] << 8) | (unsigned)p8[k];
        unsigned hh = (key * 2654435761u) >> 20;
        unsigned cur;
        for (;;) {
            cur = hmap[hh];
            if ((cur >> 12) == key) break;
            hh = (hh + 1) & 4095u;
        }
        if ((cur & 0xFFFu) == (unsigned)k) {        // winner (last write)
            int c = p6[k];
            float p1v = P1[(b << 16) | key];        // b*65536 + d*256 + e
            int w = atomicAdd(&nw, 1);
            wde[w] = (unsigned short)key;
            wv0[w] = T4 [b * 256 + c] - p1v;
            wv1[w] = T11[b * 256 + c] - p1v;
            wv2[w] = T14[b * 256 + c] - p1v;
        }
    }
    __syncthreads();
    const int nwl = nw;

    // ---- phase 4: three chained stages ----
    const int e256 = tid & 255;
    for (int s = 0; s < 3; ++s) {
        float4 acc = make_float4(0.f, 0.f, 0.f, 0.f);
        #pragma unroll
        for (int j = 0; j < 16; ++j) {
            // wave-uniform LDS broadcast; index compensates the m4 permutation
            float vv = v[(dg << 4) + ((j + roff) & 15)];
            acc.x = fmaf(vv, m4[j].x, acc.x);
            acc.y = fmaf(vv, m4[j].y, acc.y);
            acc.z = fmaf(vv, m4[j].z, acc.z);
            acc.w = fmaf(vv, m4[j].w, acc.w);
        }
        *(float4*)&pv[dg][eg << 2] = acc;
        __syncthreads();
        {   // reduce 16 -> 4 rows
            int r = tid >> 8;                       // 0..3
            float x = pv[r][e256] + pv[r + 4][e256] +
                      pv[r + 8][e256] + pv[r + 12][e256];
            __syncthreads();
            pv[r][e256] = x;
        }
        __syncthreads();
        if (tid < 256)                              // reduce 4 -> 1
            pv[0][tid] = (pv[0][tid] + pv[1][tid]) + (pv[2][tid] + pv[3][tid]);
        __syncthreads();
        const float* wvs = (s == 0) ? wv0 : (s == 1) ? wv1 : wv2;
        for (int i = tid; i < nwl; i += 1024) {
            unsigned de = wde[i];
            atomicAdd(&pv[0][de & 255u], v[de >> 8] * wvs[i]);
        }
        __syncthreads();
        if (tid < 256)
            v[tid] = pv[0][tid] * modl[s][tid];
        __syncthreads();
    }
    if (tid < 256) out[(h * 6 + b) * 256 + tid] = v[tid];
}

extern "C" void kernel_launch(void* const* d_in, const int* in_sizes, int n_in,
                              void* d_out, int out_size, void* d_ws, size_t ws_size,
                              hipStream_t stream)
{
    (void)n_in; (void)out_size; (void)d_ws; (void)ws_size;
    const float* P1  = (const float*)d_in[0];
    const float* P2  = (const float*)d_in[1];
    const float* P3  = (const float*)d_in[2];
    const float* T4  = (const float*)d_in[3];
    const int*   p5  = (const int*)d_in[4];
    const int*   p6  = (const int*)d_in[5];
    const int*   p7  = (const int*)d_in[6];
    const int*   p8  = (const int*)d_in[7];
    const float* f1  = (const float*)d_in[8];
    const float* ph1 = (const float*)d_in[9];
    const float* T11 = (const float*)d_in[10];
    const float* f2  = (const float*)d_in[11];
    const float* ph2 = (const float*)d_in[12];
    const float* T14 = (const float*)d_in[13];
    const float* f3  = (const float*)d_in[14];
    const float* ph3 = (const float*)d_in[15];
    float* out = (float*)d_out;
    int K = in_sizes[4];

    hipLaunchKernelGGL(fused_chain, dim3(96), dim3(1024), 0, stream,
                       P1, P2, P3, T4, p5, p6, p7, p8,
                       f1, ph1, T11, f2, ph2, T14, f3, ph3, out, K);
}